// Round 2
// 33134.579 us; speedup vs baseline: 1.3604x; 1.3604x over previous
//
#include <hip/hip_runtime.h>
#include <hip/hip_bf16.h>

// ---------------------------------------------------------------------------
// RecurrentCellsModel: emb lookup -> GRU scan -> LSTM scan -> linear head.
// B=128, T=2048, D=256, H=512, O=6. Float tensors f32, tokens int32.
// No fp32 MFMA on CDNA4 -> hi+lo bf16 split (~2^-17 rel err).
//
// R9: 16-col slices, 64+64 WGs, striped done-counters. 44.7ms.
// R10 theory: VGPR_Count=56 => only ~2-4 LLC loads in flight; the 32 (GRU) /
// 64 (LSTM) agent-scope ld_a16's (~800cy, L2-bypass) serialize into
// ~6-10us/step of latency vs ~1us of MFMA. Fix: issue-all-loads-upfront.
// R10 bench: container failed twice (no counters). Possible self-inflicted
// cause: LSTM 256-VGPR load phase near spill boundary -> scratch -> watchdog.
// R11: same theory, spill-safe staggering:
//   - GRU unchanged: 32 h-loads upfront (128 regs) + 16 emb loads (64 regs),
//     one latency round; accx_compute pure VALU/MFMA at iter end.
//   - LSTM: issue hg hi+lo (128 regs) + hl hi (64; peak 192) -> hg MFMA pass
//     -> issue hl lo -> hl MFMA pass hi-first-then-lo (llo latency hides
//     under 64 lhi MFMAs). 2 latency rounds; LSTM has ~2x GRU slack.
//   - poll s_sleep(1).
// Expect VGPR ~250-330 no scratch, dur 45ms -> ~28-33ms, MfmaUtil ~6%.
//
// MFMA 16x16x32 bf16 layouts (HW-verified m89/m91/m120):
//   A: a[j]=A[m=lane&15][k=(lane>>4)*8+j]; B: b[j]=B[k=(lane>>4)*8+j][n=lane&15];
//   D: d[reg]=D[row=(lane>>4)*4+reg][col=lane&15].
//
// Fingerprints: 12345 = ws too small; ~1e4 = boot timeout; ~1e2 = stall;
// 0.0476 = h_final zeros (e.g. rnn launch failure).
// ---------------------------------------------------------------------------

typedef short v8s __attribute__((ext_vector_type(8)));
typedef float v4f __attribute__((ext_vector_type(4)));
typedef unsigned long long u64;

#define T_STEPS 2048
#define RING_OFF 8192
#define DYN_LDS 150816

#define MFMA16(a, b, c) __builtin_amdgcn_mfma_f32_16x16x32_bf16((a), (b), (c), 0, 0, 0)

__device__ __forceinline__ v4f v4zero() { v4f z = {0.f, 0.f, 0.f, 0.f}; return z; }
__device__ __forceinline__ float sigf(float x) { return 1.f / (1.f + __expf(-x)); }
__device__ __forceinline__ float tanhf_fast(float x) { return 1.f - 2.f / (1.f + __expf(2.f * x)); }

__device__ __forceinline__ ushort f2us(float v) {
  __hip_bfloat16 b = __float2bfloat16(v);
  return *reinterpret_cast<ushort*>(&b);
}
__device__ __forceinline__ float us2f(ushort u) {
  __hip_bfloat16 b;
  *reinterpret_cast<ushort*>(&b) = u;
  return __bfloat162float(b);
}
__device__ __forceinline__ void cvt_hilo(float v, ushort& h, ushort& l) {
  __hip_bfloat16 bh = __float2bfloat16(v);
  float r = v - __bfloat162float(bh);
  __hip_bfloat16 bl = __float2bfloat16(r);
  h = *reinterpret_cast<ushort*>(&bh);
  l = *reinterpret_cast<ushort*>(&bl);
}
__device__ __forceinline__ void stage4(ushort* hi, ushort* lo, const float* src) {
  float4 v = *(const float4*)src;
  float a[4] = {v.x, v.y, v.z, v.w};
#pragma unroll
  for (int j = 0; j < 4; ++j) { ushort h, l; cvt_hilo(a[j], h, l); hi[j] = h; lo[j] = l; }
}
__device__ __forceinline__ void stage4h(ushort* hi, const float* src) {  // hi only
  float4 v = *(const float4*)src;
  float a[4] = {v.x, v.y, v.z, v.w};
#pragma unroll
  for (int j = 0; j < 4; ++j) hi[j] = f2us(a[j]);
}
// write-through store to LLC (no dirty L2 line)
__device__ __forceinline__ void st_wt(ushort* p, ushort v) {
  __hip_atomic_store(p, v, __ATOMIC_RELAXED, __HIP_MEMORY_SCOPE_AGENT);
}
// LLC-coherent 16B read (2 x 8B sc0/sc1 loads, coalesced+pipelined)
__device__ __forceinline__ v8s ld_a16(const ushort* p) {
  u64 a = __hip_atomic_load((const u64*)p, __ATOMIC_RELAXED, __HIP_MEMORY_SCOPE_AGENT);
  u64 b = __hip_atomic_load((const u64*)p + 1, __ATOMIC_RELAXED, __HIP_MEMORY_SCOPE_AGENT);
  union { u64 u[2]; v8s v; } r;
  r.u[0] = a; r.u[1] = b;
  return r.v;
}

__device__ __forceinline__ int poll_ge(const int* p, int tgt, long& budget) {
  while (budget > 0) {
    if (__hip_atomic_load(p, __ATOMIC_RELAXED, __HIP_MEMORY_SCOPE_AGENT) >= tgt) return 1;
    __builtin_amdgcn_s_sleep(1);
    --budget;
  }
  return 0;
}
// striped counter: 4 words, 256B apart; sum must reach tgt
__device__ __forceinline__ int poll4_ge(const int* base, int tgt, long& budget) {
  while (budget > 0) {
    int s = __hip_atomic_load(base,       __ATOMIC_RELAXED, __HIP_MEMORY_SCOPE_AGENT)
          + __hip_atomic_load(base +  64, __ATOMIC_RELAXED, __HIP_MEMORY_SCOPE_AGENT)
          + __hip_atomic_load(base + 128, __ATOMIC_RELAXED, __HIP_MEMORY_SCOPE_AGENT)
          + __hip_atomic_load(base + 192, __ATOMIC_RELAXED, __HIP_MEMORY_SCOPE_AGENT);
    if (s >= tgt) return 1;
    __builtin_amdgcn_s_sleep(1);
    --budget;
  }
  return 0;
}

__global__ void __launch_bounds__(256, 1) rnn_persistent(
    const int* __restrict__ tok,        // [128][2048] int32
    const float* __restrict__ emb,      // [32000][256] f32
    const float* __restrict__ gwih,     // [1536][256]
    const float* __restrict__ gwhh,     // [1536][512]
    const float* __restrict__ gb,       // [1536]
    const float* __restrict__ gbn,      // [512]
    const float* __restrict__ lwih,     // [2048][512]
    const float* __restrict__ lwhh,     // [2048][512]
    const float* __restrict__ lb,       // [2048]
    char* __restrict__ ws,
    int hstride, int has_lo)            // 1024/1 (full) or 512/0 (small ws)
{
  extern __shared__ char smem[];
  const int tid  = threadIdx.x;
  const int wgid = blockIdx.x;
  const bool is_gru = (wgid < 64);
  const int sub = is_gru ? wgid : (wgid - 64);
  const int bg  = sub & 1;           // batch rows [bg*64, bg*64+64)
  const int cg  = sub >> 1;          // col group 0..31, 16 cols each
  const int colbase = cg * 16;
  const int b0 = bg * 64;
  const int stripe = cg & 3;
  const int lane = tid & 63;
  const int wave = tid >> 6;         // M-tile index 0..3
  const int quad = lane >> 4;
  const int r16  = lane & 15;

  int* cnt = (int*)ws;
  int* gru_done  = cnt + bg * 256;           // 4 stripes @ +0,+64,+128,+192
  int* lstm_done = cnt + 512 + bg * 256;
  int* boot      = cnt + 1024;
  ushort* ring = (ushort*)(ws + RING_OFF);
  const int slotE = 128 * hstride;           // elems per h time-slot
  ushort* hlb = ring + 2 * slotE;            // LSTM h, 2 parities

  const int mrow  = wave * 16 + r16;            // A row in 64-row group
  const int bglob = b0 + wave * 16 + quad * 4;  // +rg = global batch row
  const int col   = colbase + r16;              // this lane's output column
  long budget = 3000000;

  if (is_gru) {
    // LDS (ushort idx): wih hi[48][264]@0, lo@12672; whh hi[48][520]@25344, lo@50304
    ushort* smemU = (ushort*)smem;
    const int WIH_HI = 0, WIH_LO = 12672, WHH_HI = 25344, WHH_LO = 50304;
    int* okf = (int*)(smem + 150528);

    for (int i = tid; i < 48 * 64; i += 256) {       // wih: 256 K, 4 f32/chunk
      int row = i >> 6, q = (i & 63) * 4;
      int gate = row >> 4, c = colbase + (row & 15);
      stage4(&smemU[WIH_HI + row * 264 + q], &smemU[WIH_LO + row * 264 + q],
             gwih + (long)(gate * 512 + c) * 256 + q);
    }
    for (int i = tid; i < 48 * 128; i += 256) {      // whh: 512 K
      int row = i >> 7, k = (i & 127) * 4;
      int gate = row >> 4, c = colbase + (row & 15);
      stage4(&smemU[WHH_HI + row * 520 + k], &smemU[WHH_LO + row * 520 + k],
             gwhh + (long)(gate * 512 + c) * 512 + k);
    }
    const float b_r  = gb[col];
    const float b_z  = gb[512 + col];
    const float b_in = gb[1024 + col];
    const float bnv  = gbn[col];
    __syncthreads();

    if (tid == 0) {
      __hip_atomic_fetch_add(boot, 1, __ATOMIC_RELEASE, __HIP_MEMORY_SCOPE_AGENT);
      long bb = 3000000;
      okf[0] = poll_ge(boot, 128, bb);
    }
    __syncthreads();
    if (!okf[0]) { if (wgid == 0 && tid == 0) st_wt(&hlb[slotE + 0], f2us(1.0e4f)); return; }

    v4f acc_r, acc_z, acc_nx;                   // r,z carry x+h; nx = x-part of n
    float hgreg[4] = {0.f, 0.f, 0.f, 0.f};
    float4 xa[16];                              // prefetched emb row chunk (t+1)

    // issue next-step token + all 16 emb float4 loads (latency hides under
    // the h-phase); each lane fetches its own row segment.
    auto prefetch_x = [&](int tn) {
      int ntok = tok[(b0 + mrow) * T_STEPS + tn];
      const float* xrow = emb + (long)ntok * 256;
#pragma unroll
      for (int kk = 0; kk < 8; ++kk) {
        xa[2 * kk]     = *(const float4*)(xrow + kk * 32 + quad * 8);
        xa[2 * kk + 1] = *(const float4*)(xrow + kk * 32 + quad * 8 + 4);
      }
    };
    // pure VALU/MFMA on landed xa regs; same accumulation order as R9.
    auto accx_compute = [&]() {
      acc_r = v4zero(); acc_z = v4zero(); acc_nx = v4zero();
#pragma unroll
      for (int kk = 0; kk < 8; ++kk) {
        float xv[8] = {xa[2 * kk].x, xa[2 * kk].y, xa[2 * kk].z, xa[2 * kk].w,
                       xa[2 * kk + 1].x, xa[2 * kk + 1].y, xa[2 * kk + 1].z, xa[2 * kk + 1].w};
        v8s ahi, alo;
#pragma unroll
        for (int j = 0; j < 8; ++j) { ushort h, l; cvt_hilo(xv[j], h, l); ahi[j] = (short)h; alo[j] = (short)l; }
        const int orr = (r16) * 264 + kk * 32 + quad * 8;
        const int oz  = (16 + r16) * 264 + kk * 32 + quad * 8;
        const int on  = (32 + r16) * 264 + kk * 32 + quad * 8;
        v8s brh = *(const v8s*)&smemU[WIH_HI + orr], brl = *(const v8s*)&smemU[WIH_LO + orr];
        v8s bzh = *(const v8s*)&smemU[WIH_HI + oz],  bzl = *(const v8s*)&smemU[WIH_LO + oz];
        v8s bnh = *(const v8s*)&smemU[WIH_HI + on],  bnl = *(const v8s*)&smemU[WIH_LO + on];
        acc_r = MFMA16(ahi, brh, acc_r); acc_r = MFMA16(alo, brh, acc_r); acc_r = MFMA16(ahi, brl, acc_r);
        acc_z = MFMA16(ahi, bzh, acc_z); acc_z = MFMA16(alo, bzh, acc_z); acc_z = MFMA16(ahi, bzl, acc_z);
        acc_nx = MFMA16(ahi, bnh, acc_nx); acc_nx = MFMA16(alo, bnh, acc_nx); acc_nx = MFMA16(ahi, bnl, acc_nx);
      }
    };

    prefetch_x(0);
    accx_compute();   // t=0 x-part

    for (int t = 0; t < T_STEPS; ++t) {
      // need: own-bg GRU step t-1 done (32 cgs); LSTM step t-2 done (ring bp)
      if (tid == 0) {
        int ok = poll4_ge(gru_done, 32 * t, budget);
        if (ok) ok = poll4_ge(lstm_done, 32 * (t - 1), budget);
        okf[0] = ok;
      }
      __syncthreads();
      if (!okf[0]) { if (tid == 0) st_wt(&hlb[slotE + 2 + wgid], f2us(100.f)); break; }

      // ---- load phase: all 32 h-loads in flight, then emb prefetch ----
      v8s ahi[16], alo[16];
      if (t > 0) {
        const ushort* hrow = ring + ((t - 1) & 1) * slotE + (b0 + mrow) * hstride;
#pragma unroll
        for (int kk = 0; kk < 16; ++kk) {
          ahi[kk] = ld_a16(&hrow[kk * 32 + quad * 8]);
          if (has_lo) alo[kk] = ld_a16(&hrow[512 + kk * 32 + quad * 8]);
        }
      }
      if (t + 1 < T_STEPS) prefetch_x(t + 1);

      // ---- MFMA phase ----
      v4f acc_nh = v4zero();
      if (t > 0) {
#pragma unroll
        for (int kk = 0; kk < 16; ++kk) {
          const int orr = (r16) * 520 + kk * 32 + quad * 8;
          const int oz  = (16 + r16) * 520 + kk * 32 + quad * 8;
          const int on  = (32 + r16) * 520 + kk * 32 + quad * 8;
          v8s brh = *(const v8s*)&smemU[WHH_HI + orr], brl = *(const v8s*)&smemU[WHH_LO + orr];
          v8s bzh = *(const v8s*)&smemU[WHH_HI + oz],  bzl = *(const v8s*)&smemU[WHH_LO + oz];
          v8s bnh = *(const v8s*)&smemU[WHH_HI + on],  bnl = *(const v8s*)&smemU[WHH_LO + on];
          acc_r = MFMA16(ahi[kk], brh, acc_r); acc_r = MFMA16(ahi[kk], brl, acc_r);
          acc_z = MFMA16(ahi[kk], bzh, acc_z); acc_z = MFMA16(ahi[kk], bzl, acc_z);
          acc_nh = MFMA16(ahi[kk], bnh, acc_nh); acc_nh = MFMA16(ahi[kk], bnl, acc_nh);
          if (has_lo) {
            acc_r = MFMA16(alo[kk], brh, acc_r);
            acc_z = MFMA16(alo[kk], bzh, acc_z);
            acc_nh = MFMA16(alo[kk], bnh, acc_nh);
          }
        }
      }

      ushort* slotT = ring + (t & 1) * slotE;
#pragma unroll
      for (int rg = 0; rg < 4; ++rg) {
        float r = sigf(acc_r[rg] + b_r);
        float z = sigf(acc_z[rg] + b_z);
        float nn = tanhf_fast(acc_nx[rg] + b_in + r * (acc_nh[rg] + bnv));
        float hnew = nn + z * (hgreg[rg] - nn);
        hgreg[rg] = hnew;
        ushort uh = f2us(hnew);
        const int rb = (bglob + rg) * hstride;
        st_wt(&slotT[rb + col], uh);
        if (has_lo) st_wt(&slotT[rb + 512 + col], f2us(hnew - us2f(uh)));
      }

      __syncthreads();   // drains all waves' write-through stores
      if (tid == 0)
        __hip_atomic_fetch_add(gru_done + stripe * 64, 1, __ATOMIC_RELAXED, __HIP_MEMORY_SCOPE_AGENT);
      if (t + 1 < T_STEPS) accx_compute();   // next step's x-part in the flag shadow
    }
  } else {
    // ---------------- LSTM: 16 cols, HI-ONLY weights ----------------
    // LDS: wl hi[64][1032] ([0,512)=wih K over hg, [512,1024)=whh K over hl)
    ushort* smemU = (ushort*)smem;
    int* okf = (int*)(smem + 132096);

    for (int i = tid; i < 64 * 256; i += 256) {
      int row = i >> 8, k = (i & 255) * 4;
      int gate = row >> 4, c = colbase + (row & 15);
      long grow = gate * 512 + c;
      const float* src = (k < 512) ? (lwih + grow * 512 + k) : (lwhh + grow * 512 + (k - 512));
      stage4h(&smemU[row * 1032 + k], src);
    }
    const float b_i = lb[col];
    const float b_f = lb[512 + col];
    const float b_g = lb[1024 + col];
    const float b_o = lb[1536 + col];
    __syncthreads();

    if (tid == 0) {
      __hip_atomic_fetch_add(boot, 1, __ATOMIC_RELEASE, __HIP_MEMORY_SCOPE_AGENT);
      long bb = 3000000;
      okf[0] = poll_ge(boot, 128, bb);
    }
    __syncthreads();
    if (!okf[0]) { if (wgid == 64 && tid == 0) st_wt(&hlb[slotE + 1], f2us(1.0e4f)); return; }

    float creg[4] = {0.f, 0.f, 0.f, 0.f};

    for (int t = 0; t < T_STEPS; ++t) {
      if (tid == 0) {
        int ok = poll4_ge(gru_done, 32 * (t + 1), budget);
        if (ok) ok = poll4_ge(lstm_done, 32 * t, budget);
        okf[0] = ok;
      }
      __syncthreads();
      if (!okf[0]) { if (tid == 0) st_wt(&hlb[slotE + 2 + wgid], f2us(100.f)); break; }

      // ---- phase A: hg hi+lo loads (32 in flight, 128 VGPRs) ----
      v8s ghi[16], glo[16];
      {
        const ushort* hrow = ring + (t & 1) * slotE + (b0 + mrow) * hstride;
#pragma unroll
        for (int kk = 0; kk < 16; ++kk) {
          ghi[kk] = ld_a16(&hrow[kk * 32 + quad * 8]);
          if (has_lo) glo[kk] = ld_a16(&hrow[512 + kk * 32 + quad * 8]);
        }
      }
      // ---- phase B: hl hi loads issued BEFORE hg MFMA (peak 192 VGPRs) ----
      v8s lhi[16], llo[16];
      const ushort* lrow = hlb + ((t - 1) & 1) * slotE + (b0 + mrow) * hstride;
      if (t > 0) {
#pragma unroll
        for (int kk = 0; kk < 16; ++kk) lhi[kk] = ld_a16(&lrow[kk * 32 + quad * 8]);
      }

      // ---- hg MFMA pass (weight K offset 0); frees ghi/glo ----
      v4f ai = v4zero(), af = v4zero(), ag = v4zero(), ao = v4zero();
#pragma unroll
      for (int kk = 0; kk < 16; ++kk) {
        v8s bi = *(const v8s*)&smemU[(r16) * 1032 + kk * 32 + quad * 8];
        v8s bf = *(const v8s*)&smemU[(16 + r16) * 1032 + kk * 32 + quad * 8];
        v8s bgv = *(const v8s*)&smemU[(32 + r16) * 1032 + kk * 32 + quad * 8];
        v8s bo = *(const v8s*)&smemU[(48 + r16) * 1032 + kk * 32 + quad * 8];
        ai = MFMA16(ghi[kk], bi, ai); af = MFMA16(ghi[kk], bf, af);
        ag = MFMA16(ghi[kk], bgv, ag); ao = MFMA16(ghi[kk], bo, ao);
        if (has_lo) {
          ai = MFMA16(glo[kk], bi, ai); af = MFMA16(glo[kk], bf, af);
          ag = MFMA16(glo[kk], bgv, ag); ao = MFMA16(glo[kk], bo, ao);
        }
      }

      if (t > 0) {
        // ---- phase C: hl lo loads; latency hides under the lhi MFMAs ----
        if (has_lo) {
#pragma unroll
          for (int kk = 0; kk < 16; ++kk) llo[kk] = ld_a16(&lrow[512 + kk * 32 + quad * 8]);
        }
        // hl MFMA pass, hi sublane first (weight K offset 512)
#pragma unroll
        for (int kk = 0; kk < 16; ++kk) {
          v8s bi = *(const v8s*)&smemU[(r16) * 1032 + 512 + kk * 32 + quad * 8];
          v8s bf = *(const v8s*)&smemU[(16 + r16) * 1032 + 512 + kk * 32 + quad * 8];
          v8s bgv = *(const v8s*)&smemU[(32 + r16) * 1032 + 512 + kk * 32 + quad * 8];
          v8s bo = *(const v8s*)&smemU[(48 + r16) * 1032 + 512 + kk * 32 + quad * 8];
          ai = MFMA16(lhi[kk], bi, ai); af = MFMA16(lhi[kk], bf, af);
          ag = MFMA16(lhi[kk], bgv, ag); ao = MFMA16(lhi[kk], bo, ao);
        }
        if (has_lo) {
#pragma unroll
          for (int kk = 0; kk < 16; ++kk) {
            v8s bi = *(const v8s*)&smemU[(r16) * 1032 + 512 + kk * 32 + quad * 8];
            v8s bf = *(const v8s*)&smemU[(16 + r16) * 1032 + 512 + kk * 32 + quad * 8];
            v8s bgv = *(const v8s*)&smemU[(32 + r16) * 1032 + 512 + kk * 32 + quad * 8];
            v8s bo = *(const v8s*)&smemU[(48 + r16) * 1032 + 512 + kk * 32 + quad * 8];
            ai = MFMA16(llo[kk], bi, ai); af = MFMA16(llo[kk], bf, af);
            ag = MFMA16(llo[kk], bgv, ag); ao = MFMA16(llo[kk], bo, ao);
          }
        }
      }

      ushort* hout = hlb + (t & 1) * slotE;
#pragma unroll
      for (int rg = 0; rg < 4; ++rg) {
        float i_ = sigf(ai[rg] + b_i), f_ = sigf(af[rg] + b_f);
        float g_ = tanhf_fast(ag[rg] + b_g), o_ = sigf(ao[rg] + b_o);
        float cn = f_ * creg[rg] + i_ * g_;
        creg[rg] = cn;
        float hv = o_ * tanhf_fast(cn);
        ushort uh = f2us(hv);
        const int rb = (bglob + rg) * hstride;
        st_wt(&hout[rb + col], uh);
        if (has_lo) st_wt(&hout[rb + 512 + col], f2us(hv - us2f(uh)));
      }

      __syncthreads();
      if (tid == 0)
        __hip_atomic_fetch_add(lstm_done + stripe * 64, 1, __ATOMIC_RELAXED, __HIP_MEMORY_SCOPE_AGENT);
    }
  }
}

// out = h_final @ head_w.T + head_b (f32). h_final = hl parity 1 hi(+lo).
__global__ void head_kernel(const char* __restrict__ ws,
                            const float* __restrict__ hw,   // [6][512]
                            const float* __restrict__ hbias,// [6]
                            float* __restrict__ out,        // [128][6]
                            int hstride, int has_lo) {
  const ushort* h1 = (const ushort*)(ws + RING_OFF) + 3 * 128 * hstride;
  const int b = blockIdx.x, l = threadIdx.x;   // 64 threads; lane l owns k=l*8..l*8+7
  const int k0 = l * 8;
  v8s hi = ld_a16(&h1[b * hstride + k0]);
  v8s lo;
  if (has_lo) lo = ld_a16(&h1[b * hstride + 512 + k0]);
  float acc[6] = {0.f, 0.f, 0.f, 0.f, 0.f, 0.f};
#pragma unroll
  for (int j = 0; j < 8; ++j) {
    float h = us2f((ushort)hi[j]);
    if (has_lo) h += us2f((ushort)lo[j]);
#pragma unroll
    for (int o = 0; o < 6; ++o) acc[o] += h * hw[o * 512 + k0 + j];
  }
#pragma unroll
  for (int o = 0; o < 6; ++o) {
    float v = acc[o];
    for (int off = 32; off > 0; off >>= 1) v += __shfl_down(v, off);
    if (l == 0) out[b * 6 + o] = v + hbias[o];
  }
}

// zero the counter region with write-through stores (no cached ws lines)
__global__ void init_ws(int* cnt) {
  int i = blockIdx.x * blockDim.x + threadIdx.x;
  if (i < 2048)
    __hip_atomic_store(cnt + i, 0, __ATOMIC_RELAXED, __HIP_MEMORY_SCOPE_AGENT);
}

__global__ void ws_too_small_marker(float* out) {
  if (threadIdx.x == 0 && blockIdx.x == 0) out[0] = 12345.0f;
}

extern "C" void kernel_launch(void* const* d_in, const int* in_sizes, int n_in,
                              void* d_out, int out_size, void* d_ws, size_t ws_size,
                              hipStream_t stream) {
  const int*   tok  = (const int*)d_in[0];
  const float* emb  = (const float*)d_in[1];
  const float* gwih = (const float*)d_in[2];
  const float* gwhh = (const float*)d_in[3];
  const float* gb   = (const float*)d_in[4];
  const float* gbn  = (const float*)d_in[5];
  const float* lwih = (const float*)d_in[6];
  const float* lwhh = (const float*)d_in[7];
  const float* lb   = (const float*)d_in[8];
  const float* hw   = (const float*)d_in[9];
  const float* hb   = (const float*)d_in[10];

  (void)in_sizes; (void)n_in; (void)out_size;

  const size_t WS_A = (size_t)RING_OFF + 4ull * 128 * 1024 * 2;  // 1,056,768
  const size_t WS_B = (size_t)RING_OFF + 4ull * 128 * 512 * 2;   //   532,480
  if (ws_size < WS_B) {
    hipLaunchKernelGGL(ws_too_small_marker, dim3(1), dim3(64), 0, stream, (float*)d_out);
    return;
  }
  const int has_lo  = (ws_size >= (size_t)WS_A) ? 1 : 0;
  const int hstride = has_lo ? 1024 : 512;

  (void)hipFuncSetAttribute(reinterpret_cast<const void*>(rnn_persistent),
                            hipFuncAttributeMaxDynamicSharedMemorySize, DYN_LDS);
  hipLaunchKernelGGL(init_ws, dim3(8), dim3(256), 0, stream, (int*)d_ws);
  hipLaunchKernelGGL(rnn_persistent, dim3(128), dim3(256), DYN_LDS, stream,
                     tok, emb, gwih, gwhh, gb, gbn, lwih, lwhh, lb,
                     (char*)d_ws, hstride, has_lo);
  hipLaunchKernelGGL(head_kernel, dim3(128), dim3(64), 0, stream,
                     (const char*)d_ws, hw, hb, (float*)d_out, hstride, has_lo);
}